// Round 3
// baseline (247.731 us; speedup 1.0000x reference)
//
#include <hip/hip_runtime.h>

// LIF recurrence: mem = tau*mem + x[t]; spike = (mem > v_th); mem *= (1-spike)
// Shapes: x [T,B,C,H,W] fp32, mem0 [1,C,H,W] fp32, out spikes [T,B,C,H,W] fp32.
// T=4, B=64, C=128, H=W=32.
//
// R1 post-mortem: 85 us/dispatch, 2.4 TB/s, VGPR=16 -> compiler serialized the
// 4 t-slice loads (1 outstanding load/wave). Latency-bound, not BW-bound.
// R2: hoist all loads (2 spatial groups x 4 timesteps = 8 independent float4
// loads in flight per thread) before any compute; nontemporal stores.
// R3: __builtin_nontemporal_store needs a clang native vector type, not
// HIP_vector_type -> use ext_vector_type(4) alias.

#ifndef LIF_T
#define LIF_T 4
#endif

typedef float vf4 __attribute__((ext_vector_type(4)));

__global__ __launch_bounds__(256) void
lif_kernel(const vf4* __restrict__ x,     // [T, N4] float4 view
           const vf4* __restrict__ mem0,  // [CHW4] float4 view (broadcast over B)
           vf4* __restrict__ out,         // [T, N4]
           int n4, int half, int chw4_mask) {
    int i = blockIdx.x * blockDim.x + threadIdx.x;
    if (i >= half) return;
    int j0 = i;
    int j1 = i + half;

    const float TAU = 0.25f;
    const float V_TH = 1.0f;

    // ---- issue ALL global loads first: 8 independent 16B loads in flight
    vf4 xa[LIF_T], xb[LIF_T];
#pragma unroll
    for (int t = 0; t < LIF_T; ++t) {
        xa[t] = x[(size_t)t * n4 + j0];
        xb[t] = x[(size_t)t * n4 + j1];
    }
    vf4 ma = mem0[j0 & chw4_mask];
    vf4 mb = mem0[j1 & chw4_mask];

    // ---- sequential scan in registers, nontemporal streaming stores
#pragma unroll
    for (int t = 0; t < LIF_T; ++t) {
        vf4 s, r;

        ma = TAU * ma + xa[t];
        s.x = (ma.x > V_TH) ? 1.0f : 0.0f;
        s.y = (ma.y > V_TH) ? 1.0f : 0.0f;
        s.z = (ma.z > V_TH) ? 1.0f : 0.0f;
        s.w = (ma.w > V_TH) ? 1.0f : 0.0f;
        ma.x = (ma.x > V_TH) ? 0.0f : ma.x;
        ma.y = (ma.y > V_TH) ? 0.0f : ma.y;
        ma.z = (ma.z > V_TH) ? 0.0f : ma.z;
        ma.w = (ma.w > V_TH) ? 0.0f : ma.w;
        __builtin_nontemporal_store(s, &out[(size_t)t * n4 + j0]);

        mb = TAU * mb + xb[t];
        r.x = (mb.x > V_TH) ? 1.0f : 0.0f;
        r.y = (mb.y > V_TH) ? 1.0f : 0.0f;
        r.z = (mb.z > V_TH) ? 1.0f : 0.0f;
        r.w = (mb.w > V_TH) ? 1.0f : 0.0f;
        mb.x = (mb.x > V_TH) ? 0.0f : mb.x;
        mb.y = (mb.y > V_TH) ? 0.0f : mb.y;
        mb.z = (mb.z > V_TH) ? 0.0f : mb.z;
        mb.w = (mb.w > V_TH) ? 0.0f : mb.w;
        __builtin_nontemporal_store(r, &out[(size_t)t * n4 + j1]);
    }
}

extern "C" void kernel_launch(void* const* d_in, const int* in_sizes, int n_in,
                              void* d_out, int out_size, void* d_ws, size_t ws_size,
                              hipStream_t stream) {
    const float* x    = (const float*)d_in[0];   // [T,B,C,H,W]
    const float* mem0 = (const float*)d_in[1];   // [1,C,H,W]
    float* out        = (float*)d_out;           // [T,B,C,H,W]

    const int T = LIF_T;
    const int total = in_sizes[0];        // T*B*C*H*W
    const int bchw  = total / T;          // per-timestep elements
    const int n4    = bchw / 4;           // float4 count per timestep (2,097,152)
    const int half  = n4 / 2;             // 2 float4 groups per thread
    const int chw4  = in_sizes[1] / 4;    // mem0 float4 count (power of 2)

    const int block = 256;
    const int grid  = (half + block - 1) / block;

    lif_kernel<<<grid, block, 0, stream>>>(
        (const vf4*)x, (const vf4*)mem0, (vf4*)out,
        n4, half, chw4 - 1);
}

// Round 4
// 246.372 us; speedup vs baseline: 1.0055x; 1.0055x over previous
//
#include <hip/hip_runtime.h>

// LIF recurrence: mem = tau*mem + x[t]; spike = (mem > v_th); mem *= (1-spike)
// Shapes: x [T,B,C,H,W] fp32, mem0 [1,C,H,W] fp32, out spikes [T,B,C,H,W] fp32.
// T=4, B=64, C=128, H=W=32.
//
// R1: 85 us, 2.4 TB/s, VGPR=16 -> loads serialized (1-2 in flight).
// R3: nt stores + "hoist": 103 us, VGPR=28 -> compiler sank the loads anyway,
//     and nt stores slowed the write stream (1.55 -> 1.29 TB/s write BW).
// R4: regular stores; asm scheduling barrier pins all 10 loads before any
//     compute/store -> one load-drain wait, stores never pollute vmcnt waits.
//     Testable proxy: VGPR must rise to ~56-64.

#ifndef LIF_T
#define LIF_T 4
#endif

typedef float vf4 __attribute__((ext_vector_type(4)));

__device__ __forceinline__ vf4 lif_step(vf4& mem, vf4 xt) {
    const float TAU = 0.25f;
    const float V_TH = 1.0f;
    vf4 s;
    mem = TAU * mem + xt;
    s.x = (mem.x > V_TH) ? 1.0f : 0.0f;
    s.y = (mem.y > V_TH) ? 1.0f : 0.0f;
    s.z = (mem.z > V_TH) ? 1.0f : 0.0f;
    s.w = (mem.w > V_TH) ? 1.0f : 0.0f;
    mem.x = (mem.x > V_TH) ? 0.0f : mem.x;
    mem.y = (mem.y > V_TH) ? 0.0f : mem.y;
    mem.z = (mem.z > V_TH) ? 0.0f : mem.z;
    mem.w = (mem.w > V_TH) ? 0.0f : mem.w;
    return s;
}

__global__ __launch_bounds__(256) void
lif_kernel(const vf4* __restrict__ x,     // [T, N4]
           const vf4* __restrict__ mem0,  // [CHW4] (broadcast over B)
           vf4* __restrict__ out,         // [T, N4]
           int n4, int half, int chw4_mask) {
    int i = blockIdx.x * blockDim.x + threadIdx.x;
    if (i >= half) return;
    const size_t j0 = (size_t)i;
    const size_t j1 = (size_t)i + (size_t)half;
    const size_t N = (size_t)n4;

    // ---- phase 1: issue ALL 10 global loads (8 x-slices + 2 mem0)
    vf4 xa0 = x[0 * N + j0];
    vf4 xb0 = x[0 * N + j1];
    vf4 xa1 = x[1 * N + j0];
    vf4 xb1 = x[1 * N + j1];
    vf4 xa2 = x[2 * N + j0];
    vf4 xb2 = x[2 * N + j1];
    vf4 xa3 = x[3 * N + j0];
    vf4 xb3 = x[3 * N + j1];
    vf4 ma  = mem0[j0 & chw4_mask];
    vf4 mb  = mem0[(j1 & chw4_mask)];

    // Scheduling fence: backend may not sink the loads below this point,
    // so all 10 are in flight together and drain with one waitcnt chain.
    asm volatile("" ::: "memory");

    // ---- phase 2: in-register scan
    vf4 s0 = lif_step(ma, xa0);
    vf4 s1 = lif_step(ma, xa1);
    vf4 s2 = lif_step(ma, xa2);
    vf4 s3 = lif_step(ma, xa3);
    vf4 r0 = lif_step(mb, xb0);
    vf4 r1 = lif_step(mb, xb1);
    vf4 r2 = lif_step(mb, xb2);
    vf4 r3 = lif_step(mb, xb3);

    // ---- phase 3: stores (loads already drained; no intermediate waits)
    out[0 * N + j0] = s0;
    out[0 * N + j1] = r0;
    out[1 * N + j0] = s1;
    out[1 * N + j1] = r1;
    out[2 * N + j0] = s2;
    out[2 * N + j1] = r2;
    out[3 * N + j0] = s3;
    out[3 * N + j1] = r3;
}

extern "C" void kernel_launch(void* const* d_in, const int* in_sizes, int n_in,
                              void* d_out, int out_size, void* d_ws, size_t ws_size,
                              hipStream_t stream) {
    const float* x    = (const float*)d_in[0];   // [T,B,C,H,W]
    const float* mem0 = (const float*)d_in[1];   // [1,C,H,W]
    float* out        = (float*)d_out;           // [T,B,C,H,W]

    const int T = LIF_T;
    const int total = in_sizes[0];        // T*B*C*H*W
    const int bchw  = total / T;          // per-timestep elements
    const int n4    = bchw / 4;           // float4 groups per timestep (2,097,152)
    const int half  = n4 / 2;             // 2 groups per thread
    const int chw4  = in_sizes[1] / 4;    // mem0 float4 count (power of 2)

    const int block = 256;
    const int grid  = (half + block - 1) / block;

    lif_kernel<<<grid, block, 0, stream>>>(
        (const vf4*)x, (const vf4*)mem0, (vf4*)out,
        n4, half, chw4 - 1);
}

// Round 5
// 244.946 us; speedup vs baseline: 1.0114x; 1.0058x over previous
//
#include <hip/hip_runtime.h>

// LIF recurrence: mem = tau*mem + x[t]; spike = (mem > v_th); mem *= (1-spike)
// Shapes: x [T,B,C,H,W] fp32, mem0 [1,C,H,W] fp32, out spikes [T,B,C,H,W] fp32.
// T=4, B=64, C=128, H=W=32.
//
// R1: 85 us, 2.4 TB/s, VGPR=16 -> ~1-2 loads in flight per wave.
// R3: nt stores regressed write stream; compiler sank hoisted loads (VGPR=28).
// R4: asm memory-clobber barrier also defeated (VGPR=24). All rounds share the
//     same compiled load->wait->use chain; MLP theory still untested.
// R5: pin each loaded value in VGPRs with asm "+v" register operands -- the
//     backend cannot sink a load past a use of its dest register. 10 loads
//     (10 KiB/wave) genuinely in flight. Proxy: VGPR_Count must be ~56-64.

#ifndef LIF_T
#define LIF_T 4
#endif

typedef float vf4 __attribute__((ext_vector_type(4)));

__device__ __forceinline__ void pin(vf4& v) {
    asm volatile("" : "+v"(v));
}

__device__ __forceinline__ vf4 lif_step(vf4& mem, vf4 xt) {
    const float TAU = 0.25f;
    const float V_TH = 1.0f;
    vf4 s;
    mem = TAU * mem + xt;
    s.x = (mem.x > V_TH) ? 1.0f : 0.0f;
    s.y = (mem.y > V_TH) ? 1.0f : 0.0f;
    s.z = (mem.z > V_TH) ? 1.0f : 0.0f;
    s.w = (mem.w > V_TH) ? 1.0f : 0.0f;
    mem.x = (mem.x > V_TH) ? 0.0f : mem.x;
    mem.y = (mem.y > V_TH) ? 0.0f : mem.y;
    mem.z = (mem.z > V_TH) ? 0.0f : mem.z;
    mem.w = (mem.w > V_TH) ? 0.0f : mem.w;
    return s;
}

__global__ __launch_bounds__(256) void
lif_kernel(const vf4* __restrict__ x,     // [T, N4]
           const vf4* __restrict__ mem0,  // [CHW4] (broadcast over B)
           vf4* __restrict__ out,         // [T, N4]
           int n4, int half, int chw4_mask) {
    int i = blockIdx.x * blockDim.x + threadIdx.x;
    if (i >= half) return;
    const size_t j0 = (size_t)i;
    const size_t j1 = (size_t)i + (size_t)half;
    const size_t N = (size_t)n4;

    // ---- phase 1: issue ALL 10 global loads (8 x-slices + 2 mem0)
    vf4 xa0 = x[0 * N + j0];
    vf4 xb0 = x[0 * N + j1];
    vf4 xa1 = x[1 * N + j0];
    vf4 xb1 = x[1 * N + j1];
    vf4 xa2 = x[2 * N + j0];
    vf4 xb2 = x[2 * N + j1];
    vf4 xa3 = x[3 * N + j0];
    vf4 xb3 = x[3 * N + j1];
    vf4 ma  = mem0[j0 & chw4_mask];
    vf4 mb  = mem0[j1 & chw4_mask];

    // Register-pin: each value must be materialized in VGPRs here, so the
    // backend cannot sink any load below this point. All 10 in flight.
    pin(xa0); pin(xb0); pin(xa1); pin(xb1);
    pin(xa2); pin(xb2); pin(xa3); pin(xb3);
    pin(ma);  pin(mb);

    // ---- phase 2: in-register scan
    vf4 s0 = lif_step(ma, xa0);
    vf4 s1 = lif_step(ma, xa1);
    vf4 s2 = lif_step(ma, xa2);
    vf4 s3 = lif_step(ma, xa3);
    vf4 r0 = lif_step(mb, xb0);
    vf4 r1 = lif_step(mb, xb1);
    vf4 r2 = lif_step(mb, xb2);
    vf4 r3 = lif_step(mb, xb3);

    // ---- phase 3: stores
    out[0 * N + j0] = s0;
    out[0 * N + j1] = r0;
    out[1 * N + j0] = s1;
    out[1 * N + j1] = r1;
    out[2 * N + j0] = s2;
    out[2 * N + j1] = r2;
    out[3 * N + j0] = s3;
    out[3 * N + j1] = r3;
}

extern "C" void kernel_launch(void* const* d_in, const int* in_sizes, int n_in,
                              void* d_out, int out_size, void* d_ws, size_t ws_size,
                              hipStream_t stream) {
    const float* x    = (const float*)d_in[0];   // [T,B,C,H,W]
    const float* mem0 = (const float*)d_in[1];   // [1,C,H,W]
    float* out        = (float*)d_out;           // [T,B,C,H,W]

    const int T = LIF_T;
    const int total = in_sizes[0];        // T*B*C*H*W
    const int bchw  = total / T;          // per-timestep elements
    const int n4    = bchw / 4;           // float4 groups per timestep (2,097,152)
    const int half  = n4 / 2;             // 2 groups per thread
    const int chw4  = in_sizes[1] / 4;    // mem0 float4 count (power of 2)

    const int block = 256;
    const int grid  = (half + block - 1) / block;

    lif_kernel<<<grid, block, 0, stream>>>(
        (const vf4*)x, (const vf4*)mem0, (vf4*)out,
        n4, half, chw4 - 1);
}